// Round 13
// baseline (283.304 us; speedup 1.0000x reference)
//
#include <hip/hip_runtime.h>
#include <hip/hip_fp16.h>

// GCN 3-layer: N=50000, E=800000, dims 128->128->128->64, fp32 in/out.
// bf16x3 MFMA GEMM (x=hi+lo, W=Whi+Wlo; x@W ~= hi@Whi+hi@Wlo+lo@Whi).
// R12: agg(layer k) fused with gemm(layer k+1) -- row-local: block=64 nodes,
// phase1 wave-aggregate (fp16 gathers + fp32 self-loop + bias) -> LDS[64][132],
// phase2 same-wave MFMA from LDS (in-register bf16 split) -> Y fp32 + Ah fp16.
// h never touches HBM (saves ~51MB/layer). gemm1 splits fp32 x in-register
// (split_kernel deleted). CSR bucketed counting sort (R8) unchanged.
// mfma_f32_16x16x32_bf16 layouts (m89): A lane l: row=l&15, k=(l>>4)*8+j;
// B: col=l&15 same k; C/D: row=(lane>>4)*4+r, col=lane&15.

#define C_IN 128
#define C_HID 128
#define C_OUT 64
#define PART_BLOCKS 256

typedef __attribute__((ext_vector_type(8))) short bf16x8;
typedef __attribute__((ext_vector_type(4))) float f32x4;

__device__ __forceinline__ unsigned short bf16_rne(float f) {
    unsigned u = __float_as_uint(f);
    unsigned r = u + 0x7FFFu + ((u >> 16) & 1u);
    return (unsigned short)(r >> 16);
}
__device__ __forceinline__ float bf16_f(unsigned short h) {
    return __uint_as_float(((unsigned)h) << 16);
}

// ---------------- CSR build: bucketed counting sort (R8) ----------------

__global__ __launch_bounds__(256) void buk_hist_kernel(const int* __restrict__ dst, int E,
                                                       int* __restrict__ bukCnt) {
    __shared__ int h[256];
    int tid = threadIdx.x;
    h[tid] = 0;
    __syncthreads();
    int chunk = (E + gridDim.x - 1) / gridDim.x;
    int lo = blockIdx.x * chunk;
    int hi = min(lo + chunk, E);
    for (int e = lo + tid; e < hi; e += 256)
        atomicAdd(&h[dst[e] >> 8], 1);
    __syncthreads();
    if (h[tid] > 0) atomicAdd(&bukCnt[tid], h[tid]);
}

__global__ __launch_bounds__(256) void buk_scan_kernel(const int* __restrict__ bukCnt,
                                                       int nbuk, int E,
                                                       int* __restrict__ bbase,
                                                       int* __restrict__ cursor) {
    __shared__ int lds[256];
    int tid = threadIdx.x;
    int v = (tid < nbuk) ? bukCnt[tid] : 0;
    lds[tid] = v;
    __syncthreads();
    for (int off = 1; off < 256; off <<= 1) {
        int u = (tid >= off) ? lds[tid - off] : 0;
        __syncthreads();
        lds[tid] += u;
        __syncthreads();
    }
    int ex = lds[tid] - v;
    if (tid < nbuk) { bbase[tid] = ex; cursor[tid] = ex; }
    if (tid == 0) bbase[nbuk] = E;
}

__global__ __launch_bounds__(256) void buk_place_kernel(const int* __restrict__ src,
                                                        const int* __restrict__ dst, int E,
                                                        int* __restrict__ cursor,
                                                        int2* __restrict__ ebuf) {
    __shared__ int h[256];
    __shared__ int base[256];
    __shared__ int c2[256];
    int tid = threadIdx.x;
    h[tid] = 0;
    c2[tid] = 0;
    __syncthreads();
    int chunk = (E + gridDim.x - 1) / gridDim.x;
    int lo = blockIdx.x * chunk;
    int hi = min(lo + chunk, E);
    for (int e = lo + tid; e < hi; e += 256)
        atomicAdd(&h[dst[e] >> 8], 1);
    __syncthreads();
    int cnt = h[tid];
    if (cnt > 0) base[tid] = atomicAdd(&cursor[tid], cnt);
    __syncthreads();
    for (int e = lo + tid; e < hi; e += 256) {
        int d = dst[e];
        int b = d >> 8;
        int slot = base[b] + atomicAdd(&c2[b], 1);
        ebuf[slot] = make_int2(src[e], d);
    }
}

__global__ __launch_bounds__(256) void buk_fill_kernel(const int2* __restrict__ ebuf,
                                                       const int* __restrict__ bbase,
                                                       int n, int E,
                                                       int* __restrict__ rowptr,
                                                       float* __restrict__ dinv,
                                                       int* __restrict__ csr) {
    __shared__ int deg[256];
    __shared__ int lds[256];
    int b = blockIdx.x;
    int tid = threadIdx.x;
    int lo = bbase[b];
    int hi = bbase[b + 1];
    int node0 = b << 8;
    deg[tid] = 0;
    __syncthreads();
    for (int e = lo + tid; e < hi; e += 256)
        atomicAdd(&deg[ebuf[e].y & 255], 1);
    __syncthreads();
    int d = deg[tid];
    lds[tid] = d;
    __syncthreads();
    for (int off = 1; off < 256; off <<= 1) {
        int u = (tid >= off) ? lds[tid - off] : 0;
        __syncthreads();
        lds[tid] += u;
        __syncthreads();
    }
    int ex = lds[tid] - d;
    int node = node0 + tid;
    if (node < n) {
        rowptr[node] = lo + ex;
        dinv[node] = rsqrtf((float)d + 1.0f);
    }
    if (tid == 0)
        rowptr[min(node0 + 256, n)] = hi;
    __syncthreads();
    deg[tid] = lo + ex;
    __syncthreads();
    for (int e = lo + tid; e < hi; e += 256) {
        int2 ed = ebuf[e];
        int slot = atomicAdd(&deg[ed.y & 255], 1);
        csr[slot] = ed.x;
    }
}

// ---- W pre-split into MFMA-frag-ordered bf16 hi/lo (all 3 layers, once) ----
__global__ __launch_bounds__(256) void wsplit_all_kernel(const float* __restrict__ W1,
                                                         const float* __restrict__ W2,
                                                         const float* __restrict__ W3,
                                                         unsigned short* __restrict__ Wf) {
    int g = blockIdx.x * 256 + threadIdx.x;   // 0..5119
    const float* W;
    int FOUT, NF, base;
    if (g < 2048)      { W = W1; FOUT = 128; NF = 2048; base = 0;     }
    else if (g < 4096) { W = W2; FOUT = 128; NF = 2048; base = 32768; g -= 2048; }
    else if (g < 5120) { W = W3; FOUT = 64;  NF = 1024; base = 65536; g -= 4096; }
    else return;
    int lane = g & 63;
    int nt = (g >> 6) & 3;
    int kt = (g >> 8) & 3;
    int ct = g >> 10;
    int kbase = kt * 32 + (lane >> 4) * 8;
    int cc = ct * 64 + nt * 16 + (lane & 15);
    unsigned short hi8[8], lo8[8];
#pragma unroll
    for (int j = 0; j < 8; ++j) {
        float w = W[(size_t)(kbase + j) * FOUT + cc];
        hi8[j] = bf16_rne(w);
        lo8[j] = bf16_rne(w - bf16_f(hi8[j]));
    }
    *(bf16x8*)&Wf[(size_t)(base + g * 8)] = *(bf16x8*)hi8;
    *(bf16x8*)&Wf[(size_t)(base + NF * 8 + g * 8)] = *(bf16x8*)lo8;
}

// in-register fp32 -> bf16 hi/lo fragment split (8 values)
__device__ __forceinline__ void split8(const float* v, bf16x8& hv, bf16x8& lv) {
#pragma unroll
    for (int j = 0; j < 8; ++j) {
        unsigned short h = bf16_rne(v[j]);
        hv[j] = (short)h;
        lv[j] = (short)bf16_rne(v[j] - bf16_f(h));
    }
}

// ------- gemm1: X(fp32)[n,128] @ W1 -> Y fp32, Yh = dinv*Y fp16 -------
// LDS-free; A split in-register from fp32 X; B frags from frag-ordered Wf.
__global__ __launch_bounds__(256, 3) void gemm1_mfma(const float* __restrict__ X,
                                                     const unsigned short* __restrict__ WfHi,
                                                     const unsigned short* __restrict__ WfLo,
                                                     const float* __restrict__ dinv,
                                                     float* __restrict__ Y,
                                                     __half* __restrict__ Yh, int n) {
    constexpr int FOUT = 128;
    int tid = threadIdx.x;
    int wv = tid >> 6, lane = tid & 63;
    int ct = blockIdx.x & 1;
    int rt = blockIdx.x >> 1;
    int col0 = ct * 64;
    int row0 = rt * 64 + wv * 16;

    int rA = row0 + (lane & 15);
    if (rA > n - 1) rA = n - 1;
    const float* px = X + (size_t)rA * 128 + ((lane >> 4) * 8);
    bf16x8 ah[4], al[4];
#pragma unroll
    for (int kt = 0; kt < 4; ++kt) {
        float v[8];
        *(float4*)&v[0] = *(const float4*)(px + kt * 32);
        *(float4*)&v[4] = *(const float4*)(px + kt * 32 + 4);
        split8(v, ah[kt], al[kt]);
    }

    const bf16x8* bhp = (const bf16x8*)WfHi + (size_t)ct * 1024 + lane;
    const bf16x8* blp = (const bf16x8*)WfLo + (size_t)ct * 1024 + lane;

    f32x4 acc[4];
#pragma unroll
    for (int nt = 0; nt < 4; ++nt) acc[nt] = (f32x4){0.f, 0.f, 0.f, 0.f};

#pragma unroll
    for (int kt = 0; kt < 4; ++kt) {
        bf16x8 bh[4], bl[4];
#pragma unroll
        for (int nt = 0; nt < 4; ++nt) {
            bh[nt] = bhp[(kt * 4 + nt) * 64];
            bl[nt] = blp[(kt * 4 + nt) * 64];
        }
#pragma unroll
        for (int nt = 0; nt < 4; ++nt) {
            acc[nt] = __builtin_amdgcn_mfma_f32_16x16x32_bf16(ah[kt], bh[nt], acc[nt], 0, 0, 0);
            acc[nt] = __builtin_amdgcn_mfma_f32_16x16x32_bf16(ah[kt], bl[nt], acc[nt], 0, 0, 0);
            acc[nt] = __builtin_amdgcn_mfma_f32_16x16x32_bf16(al[kt], bh[nt], acc[nt], 0, 0, 0);
        }
    }

#pragma unroll
    for (int r = 0; r < 4; ++r) {
        int grow = row0 + (lane >> 4) * 4 + r;
        if (grow < n) {
            float di = dinv[grow];
#pragma unroll
            for (int nt = 0; nt < 4; ++nt) {
                float v = acc[nt][r];
                size_t off = (size_t)grow * FOUT + col0 + nt * 16 + (lane & 15);
                Y[off] = v;
                Yh[off] = __float2half(v * di);
            }
        }
    }
}

// ---------------- aggregate gather helpers (fp16) ----------------
template <int NB, bool MASK>
__device__ __forceinline__ void batch_f128(const int* __restrict__ csr, int j, int rem,
                                           const __half* __restrict__ xwh, int lane,
                                           float2* acc) {
    int s[NB];
#pragma unroll
    for (int k = 0; k < NB; ++k) {
        int jj = MASK ? (j + ((k < rem) ? k : 0)) : (j + k);
        s[k] = csr[jj];
    }
    float2 v[NB];
#pragma unroll
    for (int k = 0; k < NB; ++k) {
        __half2 hv = ((const __half2*)(xwh + (size_t)s[k] * 128))[lane];
        v[k] = __half22float2(hv);
    }
#pragma unroll
    for (int k = 0; k < NB; ++k) {
        float m = (!MASK || (k < rem)) ? 1.0f : 0.0f;
        acc[k & 3].x = fmaf(v[k].x, m, acc[k & 3].x);
        acc[k & 3].y = fmaf(v[k].y, m, acc[k & 3].y);
    }
}

template <int NB, bool MASK>
__device__ __forceinline__ void batch_f64(const int* __restrict__ csr, int j, int rem,
                                          const __half* __restrict__ xwh, int lane,
                                          float* acc) {
    int s[NB];
#pragma unroll
    for (int k = 0; k < NB; ++k) {
        int jj = MASK ? (j + ((k < rem) ? k : 0)) : (j + k);
        s[k] = csr[jj];
    }
    float v[NB];
#pragma unroll
    for (int k = 0; k < NB; ++k)
        v[k] = __half2float(xwh[(size_t)s[k] * 64 + lane]);
#pragma unroll
    for (int k = 0; k < NB; ++k) {
        float m = (!MASK || (k < rem)) ? 1.0f : 0.0f;
        acc[k & 3] = fmaf(v[k], m, acc[k & 3]);
    }
}

// ------- fused: h = dinv[i]*sum xwh[src] + xw[i]*dinv^2 + b  (phase 1, ->LDS)
//         then Y = h @ W (phase 2, MFMA from LDS)  -> Y fp32 + Yh fp16 -------
// Block = 64 nodes (4 waves x 16). Waves touch only their own LDS rows: no barrier.
template <int FOUT>
__global__ __launch_bounds__(256, 3) void fused_agg_gemm(const int* __restrict__ rowptr,
                                                         const int* __restrict__ csr,
                                                         const float* __restrict__ xw,
                                                         const __half* __restrict__ xwh,
                                                         const float* __restrict__ dinv,
                                                         const float* __restrict__ bias,
                                                         const unsigned short* __restrict__ WfHi,
                                                         const unsigned short* __restrict__ WfLo,
                                                         float* __restrict__ Y,
                                                         __half* __restrict__ Yh, int n) {
    constexpr int CTILES = FOUT / 64;   // 2 or 1
    __shared__ float hl[64][132];       // 33.8 KB, +4 pad (2-way-free banks)

    int tid = threadIdx.x;
    int wv = tid >> 6, lane = tid & 63;
    int node0 = blockIdx.x * 64;

    // ---- phase 1: aggregate 16 nodes per wave into LDS ----
    for (int nn = 0; nn < 16; ++nn) {
        int nodeLocal = wv * 16 + nn;
        int i0 = node0 + nodeLocal;
        if (i0 >= n) {
            ((float2*)&hl[nodeLocal][0])[lane] = make_float2(0.f, 0.f);
            continue;
        }
        int i = __builtin_amdgcn_readfirstlane(i0);
        float di = dinv[i];
        float d2 = di * di;
        int j = rowptr[i];
        int end = rowptr[i + 1];
        j = __builtin_amdgcn_readfirstlane(j);
        end = __builtin_amdgcn_readfirstlane(end);

        float2 x0 = ((const float2*)(xw + (size_t)i * 128))[lane];
        float2 acc[4];
        acc[0] = acc[1] = acc[2] = acc[3] = make_float2(0.f, 0.f);
        for (; j + 16 <= end; j += 16) batch_f128<16, false>(csr, j, 0, xwh, lane, acc);
        if (j + 8 <= end) { batch_f128<8, false>(csr, j, 0, xwh, lane, acc); j += 8; }
        if (j + 4 <= end) { batch_f128<4, false>(csr, j, 0, xwh, lane, acc); j += 4; }
        int rem = end - j;
        if (rem > 0) batch_f128<4, true>(csr, j, rem, xwh, lane, acc);

        float2 bv = ((const float2*)bias)[lane];
        float2 o;
        o.x = fmaf(di, (acc[0].x + acc[1].x) + (acc[2].x + acc[3].x),
                   fmaf(x0.x, d2, bv.x));
        o.y = fmaf(di, (acc[0].y + acc[1].y) + (acc[2].y + acc[3].y),
                   fmaf(x0.y, d2, bv.y));
        ((float2*)&hl[nodeLocal][0])[lane] = o;
    }

    // ---- phase 2: MFMA from own wave's 16 LDS rows ----
    int rowL = wv * 16 + (lane & 15);
    bf16x8 ah[4], al[4];
#pragma unroll
    for (int kt = 0; kt < 4; ++kt) {
        int cb = kt * 32 + (lane >> 4) * 8;
        float v[8];
        *(float4*)&v[0] = *(const float4*)&hl[rowL][cb];
        *(float4*)&v[4] = *(const float4*)&hl[rowL][cb + 4];
        split8(v, ah[kt], al[kt]);
    }

#pragma unroll
    for (int ct = 0; ct < CTILES; ++ct) {
        const bf16x8* bhp = (const bf16x8*)WfHi + (size_t)ct * 1024 + lane;
        const bf16x8* blp = (const bf16x8*)WfLo + (size_t)ct * 1024 + lane;
        f32x4 acc[4];
#pragma unroll
        for (int nt = 0; nt < 4; ++nt) acc[nt] = (f32x4){0.f, 0.f, 0.f, 0.f};
#pragma unroll
        for (int kt = 0; kt < 4; ++kt) {
            bf16x8 bh[4], bl[4];
#pragma unroll
            for (int nt = 0; nt < 4; ++nt) {
                bh[nt] = bhp[(kt * 4 + nt) * 64];
                bl[nt] = blp[(kt * 4 + nt) * 64];
            }
#pragma unroll
            for (int nt = 0; nt < 4; ++nt) {
                acc[nt] = __builtin_amdgcn_mfma_f32_16x16x32_bf16(ah[kt], bh[nt], acc[nt], 0, 0, 0);
                acc[nt] = __builtin_amdgcn_mfma_f32_16x16x32_bf16(ah[kt], bl[nt], acc[nt], 0, 0, 0);
                acc[nt] = __builtin_amdgcn_mfma_f32_16x16x32_bf16(al[kt], bh[nt], acc[nt], 0, 0, 0);
            }
        }
#pragma unroll
        for (int r = 0; r < 4; ++r) {
            int grow = node0 + wv * 16 + (lane >> 4) * 4 + r;
            if (grow < n) {
                float di = dinv[grow];
#pragma unroll
                for (int nt = 0; nt < 4; ++nt) {
                    float v = acc[nt][r];
                    size_t off = (size_t)grow * FOUT + ct * 64 + nt * 16 + (lane & 15);
                    Y[off] = v;
                    Yh[off] = __float2half(v * di);
                }
            }
        }
    }
}

// --- final aggregate (F=64): out = dinv*sum xwh[src] + xw*dinv^2 + b, relu ---
__global__ __launch_bounds__(256) void agg64_kernel(const int* __restrict__ rowptr,
                                                    const int* __restrict__ csr,
                                                    const float* __restrict__ xw,
                                                    const __half* __restrict__ xwh,
                                                    const float* __restrict__ dinv,
                                                    const float* __restrict__ bias,
                                                    float* __restrict__ out, int n) {
    int wave = threadIdx.x >> 6;
    int lane = threadIdx.x & 63;
    int i0 = blockIdx.x * 4 + wave;
    if (i0 >= n) return;
    int i = __builtin_amdgcn_readfirstlane(i0);
    float di = dinv[i];
    float d2 = di * di;
    int j = rowptr[i];
    int end = rowptr[i + 1];
    j = __builtin_amdgcn_readfirstlane(j);
    end = __builtin_amdgcn_readfirstlane(end);

    float x0 = xw[(size_t)i * 64 + lane];
    float acc[4] = {0.f, 0.f, 0.f, 0.f};
    for (; j + 16 <= end; j += 16) batch_f64<16, false>(csr, j, 0, xwh, lane, acc);
    if (j + 8 <= end) { batch_f64<8, false>(csr, j, 0, xwh, lane, acc); j += 8; }
    if (j + 4 <= end) { batch_f64<4, false>(csr, j, 0, xwh, lane, acc); j += 4; }
    int rem = end - j;
    if (rem > 0) batch_f64<4, true>(csr, j, rem, xwh, lane, acc);

    float o = fmaf(di, (acc[0] + acc[1]) + (acc[2] + acc[3]),
                   fmaf(x0, d2, bias[lane]));
    o = fmaxf(o, 0.f);
    out[(size_t)i * 64 + lane] = o;
}

extern "C" void kernel_launch(void* const* d_in, const int* in_sizes, int n_in,
                              void* d_out, int out_size, void* d_ws, size_t ws_size,
                              hipStream_t stream) {
    const float* x  = (const float*)d_in[0];
    const int*   ei = (const int*)d_in[1];
    const float* W1 = (const float*)d_in[2];
    const float* b1 = (const float*)d_in[3];
    const float* W2 = (const float*)d_in[4];
    const float* b2 = (const float*)d_in[5];
    const float* W3 = (const float*)d_in[6];
    const float* b3 = (const float*)d_in[7];
    float* out = (float*)d_out;

    int E = in_sizes[1] / 2;
    int n = in_sizes[0] / C_IN;
    const int* src = ei;
    const int* dst = ei + E;
    int nbuk = (n + 255) >> 8;

    // workspace layout (ping-pong Y/Ah pairs)
    float*          Ya   = (float*)d_ws;                        // [n*128]
    __half*         Aha  = (__half*)(Ya + (size_t)n * C_HID);   // [n*128]
    float*          Yb   = (float*)(Aha + (size_t)n * C_HID);   // [n*128]
    __half*         Ahb  = (__half*)(Yb + (size_t)n * C_HID);   // [n*128]
    unsigned short* Wf   = (unsigned short*)(Ahb + (size_t)n * C_HID); // [81920]
    int2*           ebuf = (int2*)(Wf + 81920);                 // [E]
    int*            csr  = (int*)(ebuf + E);                    // [E]
    float*          dinv = (float*)(csr + E);                   // [n]
    int*            rowptr = (int*)(dinv + n);                  // [n+1]
    int*            bukCnt = rowptr + n + 1;                    // [256]
    int*            bbase  = bukCnt + 256;                      // [nbuk+1]
    int*            cursor = bbase + 256 + 1;                   // [256]

    unsigned short* W1h = Wf;
    unsigned short* W1l = Wf + 16384;
    unsigned short* W2h = Wf + 32768;
    unsigned short* W2l = Wf + 49152;
    unsigned short* W3h = Wf + 65536;
    unsigned short* W3l = Wf + 73728;

    // ---- CSR build ----
    hipMemsetAsync(bukCnt, 0, 256 * sizeof(int), stream);
    buk_hist_kernel<<<PART_BLOCKS, 256, 0, stream>>>(dst, E, bukCnt);
    buk_scan_kernel<<<1, 256, 0, stream>>>(bukCnt, nbuk, E, bbase, cursor);
    buk_place_kernel<<<PART_BLOCKS, 256, 0, stream>>>(src, dst, E, cursor, ebuf);
    buk_fill_kernel<<<nbuk, 256, 0, stream>>>(ebuf, bbase, n, E, rowptr, dinv, csr);

    // ---- one-time W frag split ----
    wsplit_all_kernel<<<20, 256, 0, stream>>>(W1, W2, W3, Wf);

    int rowTiles = (n + 63) / 64;   // 782
    int aggBlocks = (n + 3) / 4;

    // ---- layer 1 gemm (fp32 x, in-register split) ----
    gemm1_mfma<<<rowTiles * 2, 256, 0, stream>>>(x, W1h, W1l, dinv, Ya, Aha, n);
    // ---- agg1 + gemm2 fused ----
    fused_agg_gemm<C_HID><<<rowTiles, 256, 0, stream>>>(rowptr, csr, Ya, Aha, dinv, b1,
                                                        W2h, W2l, Yb, Ahb, n);
    // ---- agg2 + gemm3 fused ----
    fused_agg_gemm<C_OUT><<<rowTiles, 256, 0, stream>>>(rowptr, csr, Yb, Ahb, dinv, b2,
                                                        W3h, W3l, Ya, Aha, n);
    // ---- final agg3 + relu ----
    agg64_kernel<<<aggBlocks, 256, 0, stream>>>(rowptr, csr, Ya, Aha, dinv, b3, out, n);
}

// Round 14
// 268.366 us; speedup vs baseline: 1.0557x; 1.0557x over previous
//
#include <hip/hip_runtime.h>
#include <hip/hip_fp16.h>

// GCN 3-layer: N=50000, E=800000, dims 128->128->128->64, fp32 in/out.
// bf16x3 MFMA GEMM (x=hi+lo, W=Whi+Wlo; x@W ~= hi@Whi+hi@Wlo+lo@Whi).
// R13 = R11 structure (best: 278us) + gemm1 reads fp32 x with in-register
// split (split_kernel deleted). R12 lesson: fusing agg+gemm drops gather TLP
// (occupancy 17%) and regresses -- keep latency-bound agg standalone.
// mfma_f32_16x16x32_bf16 layouts (m89): A lane l: row=l&15, k=(l>>4)*8+j;
// B: col=l&15 same k; C/D: row=(lane>>4)*4+r, col=lane&15.

#define C_IN 128
#define C_HID 128
#define C_OUT 64
#define PART_BLOCKS 256

typedef __attribute__((ext_vector_type(8))) short bf16x8;
typedef __attribute__((ext_vector_type(4))) float f32x4;

__device__ __forceinline__ unsigned short bf16_rne(float f) {
    unsigned u = __float_as_uint(f);
    unsigned r = u + 0x7FFFu + ((u >> 16) & 1u);
    return (unsigned short)(r >> 16);
}
__device__ __forceinline__ float bf16_f(unsigned short h) {
    return __uint_as_float(((unsigned)h) << 16);
}

// ---------------- CSR build: bucketed counting sort (R8) ----------------

__global__ __launch_bounds__(256) void buk_hist_kernel(const int* __restrict__ dst, int E,
                                                       int* __restrict__ bukCnt) {
    __shared__ int h[256];
    int tid = threadIdx.x;
    h[tid] = 0;
    __syncthreads();
    int chunk = (E + gridDim.x - 1) / gridDim.x;
    int lo = blockIdx.x * chunk;
    int hi = min(lo + chunk, E);
    for (int e = lo + tid; e < hi; e += 256)
        atomicAdd(&h[dst[e] >> 8], 1);
    __syncthreads();
    if (h[tid] > 0) atomicAdd(&bukCnt[tid], h[tid]);
}

__global__ __launch_bounds__(256) void buk_scan_kernel(const int* __restrict__ bukCnt,
                                                       int nbuk, int E,
                                                       int* __restrict__ bbase,
                                                       int* __restrict__ cursor) {
    __shared__ int lds[256];
    int tid = threadIdx.x;
    int v = (tid < nbuk) ? bukCnt[tid] : 0;
    lds[tid] = v;
    __syncthreads();
    for (int off = 1; off < 256; off <<= 1) {
        int u = (tid >= off) ? lds[tid - off] : 0;
        __syncthreads();
        lds[tid] += u;
        __syncthreads();
    }
    int ex = lds[tid] - v;
    if (tid < nbuk) { bbase[tid] = ex; cursor[tid] = ex; }
    if (tid == 0) bbase[nbuk] = E;
}

__global__ __launch_bounds__(256) void buk_place_kernel(const int* __restrict__ src,
                                                        const int* __restrict__ dst, int E,
                                                        int* __restrict__ cursor,
                                                        int2* __restrict__ ebuf) {
    __shared__ int h[256];
    __shared__ int base[256];
    __shared__ int c2[256];
    int tid = threadIdx.x;
    h[tid] = 0;
    c2[tid] = 0;
    __syncthreads();
    int chunk = (E + gridDim.x - 1) / gridDim.x;
    int lo = blockIdx.x * chunk;
    int hi = min(lo + chunk, E);
    for (int e = lo + tid; e < hi; e += 256)
        atomicAdd(&h[dst[e] >> 8], 1);
    __syncthreads();
    int cnt = h[tid];
    if (cnt > 0) base[tid] = atomicAdd(&cursor[tid], cnt);
    __syncthreads();
    for (int e = lo + tid; e < hi; e += 256) {
        int d = dst[e];
        int b = d >> 8;
        int slot = base[b] + atomicAdd(&c2[b], 1);
        ebuf[slot] = make_int2(src[e], d);
    }
}

__global__ __launch_bounds__(256) void buk_fill_kernel(const int2* __restrict__ ebuf,
                                                       const int* __restrict__ bbase,
                                                       int n, int E,
                                                       int* __restrict__ rowptr,
                                                       float* __restrict__ dinv,
                                                       int* __restrict__ csr) {
    __shared__ int deg[256];
    __shared__ int lds[256];
    int b = blockIdx.x;
    int tid = threadIdx.x;
    int lo = bbase[b];
    int hi = bbase[b + 1];
    int node0 = b << 8;
    deg[tid] = 0;
    __syncthreads();
    for (int e = lo + tid; e < hi; e += 256)
        atomicAdd(&deg[ebuf[e].y & 255], 1);
    __syncthreads();
    int d = deg[tid];
    lds[tid] = d;
    __syncthreads();
    for (int off = 1; off < 256; off <<= 1) {
        int u = (tid >= off) ? lds[tid - off] : 0;
        __syncthreads();
        lds[tid] += u;
        __syncthreads();
    }
    int ex = lds[tid] - d;
    int node = node0 + tid;
    if (node < n) {
        rowptr[node] = lo + ex;
        dinv[node] = rsqrtf((float)d + 1.0f);
    }
    if (tid == 0)
        rowptr[min(node0 + 256, n)] = hi;
    __syncthreads();
    deg[tid] = lo + ex;
    __syncthreads();
    for (int e = lo + tid; e < hi; e += 256) {
        int2 ed = ebuf[e];
        int slot = atomicAdd(&deg[ed.y & 255], 1);
        csr[slot] = ed.x;
    }
}

// ---- W pre-split into MFMA-frag-ordered bf16 hi/lo (all 3 layers, once) ----
__global__ __launch_bounds__(256) void wsplit_all_kernel(const float* __restrict__ W1,
                                                         const float* __restrict__ W2,
                                                         const float* __restrict__ W3,
                                                         unsigned short* __restrict__ Wf) {
    int g = blockIdx.x * 256 + threadIdx.x;   // 0..5119
    const float* W;
    int FOUT, NF, base;
    if (g < 2048)      { W = W1; FOUT = 128; NF = 2048; base = 0;     }
    else if (g < 4096) { W = W2; FOUT = 128; NF = 2048; base = 32768; g -= 2048; }
    else if (g < 5120) { W = W3; FOUT = 64;  NF = 1024; base = 65536; g -= 4096; }
    else return;
    int lane = g & 63;
    int nt = (g >> 6) & 3;
    int kt = (g >> 8) & 3;
    int ct = g >> 10;
    int kbase = kt * 32 + (lane >> 4) * 8;
    int cc = ct * 64 + nt * 16 + (lane & 15);
    unsigned short hi8[8], lo8[8];
#pragma unroll
    for (int j = 0; j < 8; ++j) {
        float w = W[(size_t)(kbase + j) * FOUT + cc];
        hi8[j] = bf16_rne(w);
        lo8[j] = bf16_rne(w - bf16_f(hi8[j]));
    }
    *(bf16x8*)&Wf[(size_t)(base + g * 8)] = *(bf16x8*)hi8;
    *(bf16x8*)&Wf[(size_t)(base + NF * 8 + g * 8)] = *(bf16x8*)lo8;
}

// in-register fp32 -> bf16 hi/lo fragment split (8 values)
__device__ __forceinline__ void split8(const float* v, bf16x8& hv, bf16x8& lv) {
#pragma unroll
    for (int j = 0; j < 8; ++j) {
        unsigned short h = bf16_rne(v[j]);
        hv[j] = (short)h;
        lv[j] = (short)bf16_rne(v[j] - bf16_f(h));
    }
}

// ------- gemm1: X(fp32)[n,128] @ W1 -> Y fp32, Yh = dinv*Y fp16 -------
// LDS-free; A split in-register from fp32 X; B frags from frag-ordered Wf.
__global__ __launch_bounds__(256, 3) void gemm1_mfma(const float* __restrict__ X,
                                                     const unsigned short* __restrict__ WfHi,
                                                     const unsigned short* __restrict__ WfLo,
                                                     const float* __restrict__ dinv,
                                                     float* __restrict__ Y,
                                                     __half* __restrict__ Yh, int n) {
    constexpr int FOUT = 128;
    int tid = threadIdx.x;
    int wv = tid >> 6, lane = tid & 63;
    int ct = blockIdx.x & 1;
    int rt = blockIdx.x >> 1;
    int col0 = ct * 64;
    int row0 = rt * 64 + wv * 16;

    int rA = row0 + (lane & 15);
    if (rA > n - 1) rA = n - 1;
    const float* px = X + (size_t)rA * 128 + ((lane >> 4) * 8);
    bf16x8 ah[4], al[4];
#pragma unroll
    for (int kt = 0; kt < 4; ++kt) {
        float v[8];
        *(float4*)&v[0] = *(const float4*)(px + kt * 32);
        *(float4*)&v[4] = *(const float4*)(px + kt * 32 + 4);
        split8(v, ah[kt], al[kt]);
    }

    const bf16x8* bhp = (const bf16x8*)WfHi + (size_t)ct * 1024 + lane;
    const bf16x8* blp = (const bf16x8*)WfLo + (size_t)ct * 1024 + lane;

    f32x4 acc[4];
#pragma unroll
    for (int nt = 0; nt < 4; ++nt) acc[nt] = (f32x4){0.f, 0.f, 0.f, 0.f};

#pragma unroll
    for (int kt = 0; kt < 4; ++kt) {
        bf16x8 bh[4], bl[4];
#pragma unroll
        for (int nt = 0; nt < 4; ++nt) {
            bh[nt] = bhp[(kt * 4 + nt) * 64];
            bl[nt] = blp[(kt * 4 + nt) * 64];
        }
#pragma unroll
        for (int nt = 0; nt < 4; ++nt) {
            acc[nt] = __builtin_amdgcn_mfma_f32_16x16x32_bf16(ah[kt], bh[nt], acc[nt], 0, 0, 0);
            acc[nt] = __builtin_amdgcn_mfma_f32_16x16x32_bf16(ah[kt], bl[nt], acc[nt], 0, 0, 0);
            acc[nt] = __builtin_amdgcn_mfma_f32_16x16x32_bf16(al[kt], bh[nt], acc[nt], 0, 0, 0);
        }
    }

#pragma unroll
    for (int r = 0; r < 4; ++r) {
        int grow = row0 + (lane >> 4) * 4 + r;
        if (grow < n) {
            float di = dinv[grow];
#pragma unroll
            for (int nt = 0; nt < 4; ++nt) {
                float v = acc[nt][r];
                size_t off = (size_t)grow * FOUT + col0 + nt * 16 + (lane & 15);
                Y[off] = v;
                Yh[off] = __float2half(v * di);
            }
        }
    }
}

// ------- gemm (layers 2,3): (Xhi+Xlo)[n,128] @ W -> Y fp32, Yh = dinv*Y fp16 -------
template <int FOUT>
__global__ __launch_bounds__(256, 3) void gemm_mfma(const unsigned short* __restrict__ Xhi,
                                                    const unsigned short* __restrict__ Xlo,
                                                    const unsigned short* __restrict__ WfHi,
                                                    const unsigned short* __restrict__ WfLo,
                                                    const float* __restrict__ dinv,
                                                    float* __restrict__ Y,
                                                    __half* __restrict__ Yh, int n) {
    constexpr int CTILES = FOUT / 64;   // 2 (F=128) or 1 (F=64)
    int tid = threadIdx.x;
    int wv = tid >> 6, lane = tid & 63;
    int ct = (CTILES == 1) ? 0 : (blockIdx.x % CTILES);
    int rt = blockIdx.x / CTILES;
    int col0 = ct * 64;
    int row0 = rt * 64 + wv * 16;

    int rA = row0 + (lane & 15);
    if (rA > n - 1) rA = n - 1;
    const unsigned short* ph = Xhi + (size_t)rA * 128 + ((lane >> 4) * 8);
    const unsigned short* pl = Xlo + (size_t)rA * 128 + ((lane >> 4) * 8);
    bf16x8 ah[4], al[4];
#pragma unroll
    for (int kt = 0; kt < 4; ++kt) {
        ah[kt] = *(const bf16x8*)(ph + kt * 32);
        al[kt] = *(const bf16x8*)(pl + kt * 32);
    }

    const bf16x8* bhp = (const bf16x8*)WfHi + (size_t)ct * 1024 + lane;
    const bf16x8* blp = (const bf16x8*)WfLo + (size_t)ct * 1024 + lane;

    f32x4 acc[4];
#pragma unroll
    for (int nt = 0; nt < 4; ++nt) acc[nt] = (f32x4){0.f, 0.f, 0.f, 0.f};

#pragma unroll
    for (int kt = 0; kt < 4; ++kt) {
        bf16x8 bh[4], bl[4];
#pragma unroll
        for (int nt = 0; nt < 4; ++nt) {
            bh[nt] = bhp[(kt * 4 + nt) * 64];
            bl[nt] = blp[(kt * 4 + nt) * 64];
        }
#pragma unroll
        for (int nt = 0; nt < 4; ++nt) {
            acc[nt] = __builtin_amdgcn_mfma_f32_16x16x32_bf16(ah[kt], bh[nt], acc[nt], 0, 0, 0);
            acc[nt] = __builtin_amdgcn_mfma_f32_16x16x32_bf16(ah[kt], bl[nt], acc[nt], 0, 0, 0);
            acc[nt] = __builtin_amdgcn_mfma_f32_16x16x32_bf16(al[kt], bh[nt], acc[nt], 0, 0, 0);
        }
    }

#pragma unroll
    for (int r = 0; r < 4; ++r) {
        int grow = row0 + (lane >> 4) * 4 + r;
        if (grow < n) {
            float di = dinv[grow];
#pragma unroll
            for (int nt = 0; nt < 4; ++nt) {
                float v = acc[nt][r];
                size_t off = (size_t)grow * FOUT + col0 + nt * 16 + (lane & 15);
                Y[off] = v;
                Yh[off] = __float2half(v * di);
            }
        }
    }
}

// ---------------- aggregate helpers (fp16 gathers) ----------------
template <int NB, bool MASK>
__device__ __forceinline__ void batch_f128(const int* __restrict__ csr, int j, int rem,
                                           const __half* __restrict__ xwh, int lane,
                                           float2* acc) {
    int s[NB];
#pragma unroll
    for (int k = 0; k < NB; ++k) {
        int jj = MASK ? (j + ((k < rem) ? k : 0)) : (j + k);
        s[k] = csr[jj];
    }
    float2 v[NB];
#pragma unroll
    for (int k = 0; k < NB; ++k) {
        __half2 hv = ((const __half2*)(xwh + (size_t)s[k] * 128))[lane];
        v[k] = __half22float2(hv);
    }
#pragma unroll
    for (int k = 0; k < NB; ++k) {
        float m = (!MASK || (k < rem)) ? 1.0f : 0.0f;
        acc[k & 3].x = fmaf(v[k].x, m, acc[k & 3].x);
        acc[k & 3].y = fmaf(v[k].y, m, acc[k & 3].y);
    }
}

template <int NB, bool MASK>
__device__ __forceinline__ void batch_f64(const int* __restrict__ csr, int j, int rem,
                                          const __half* __restrict__ xwh, int lane,
                                          float* acc) {
    int s[NB];
#pragma unroll
    for (int k = 0; k < NB; ++k) {
        int jj = MASK ? (j + ((k < rem) ? k : 0)) : (j + k);
        s[k] = csr[jj];
    }
    float v[NB];
#pragma unroll
    for (int k = 0; k < NB; ++k)
        v[k] = __half2float(xwh[(size_t)s[k] * 64 + lane]);
#pragma unroll
    for (int k = 0; k < NB; ++k) {
        float m = (!MASK || (k < rem)) ? 1.0f : 0.0f;
        acc[k & 3] = fmaf(v[k], m, acc[k & 3]);
    }
}

// --- fused aggregate: o = dinv[i]*sum_j xwh[src_j] + xw[i]*dinv^2 + b ---
// MODE 0 (F=128): write bf16 hi/lo pair (next gemm's A operand), no relu.
// MODE 1 (F=64): write fp32 + relu (final output).
template <int F, int MODE>
__global__ __launch_bounds__(256) void agg_kernel(const int* __restrict__ rowptr,
                                                  const int* __restrict__ csr,
                                                  const float* __restrict__ xw,
                                                  const __half* __restrict__ xwh,
                                                  const float* __restrict__ dinv,
                                                  const float* __restrict__ bias,
                                                  float* __restrict__ out,
                                                  unsigned short* __restrict__ outHi,
                                                  unsigned short* __restrict__ outLo,
                                                  int n) {
    int wave = threadIdx.x >> 6;
    int lane = threadIdx.x & 63;
    int i0 = blockIdx.x * 4 + wave;
    if (i0 >= n) return;
    int i = __builtin_amdgcn_readfirstlane(i0);
    float di = dinv[i];
    float d2 = di * di;
    int j = rowptr[i];
    int end = rowptr[i + 1];
    j = __builtin_amdgcn_readfirstlane(j);
    end = __builtin_amdgcn_readfirstlane(end);

    if constexpr (F == 128) {
        float2 x0 = ((const float2*)(xw + (size_t)i * F))[lane];
        float2 acc[4];
        acc[0] = acc[1] = acc[2] = acc[3] = make_float2(0.f, 0.f);

        for (; j + 16 <= end; j += 16) batch_f128<16, false>(csr, j, 0, xwh, lane, acc);
        if (j + 8 <= end) { batch_f128<8, false>(csr, j, 0, xwh, lane, acc); j += 8; }
        if (j + 4 <= end) { batch_f128<4, false>(csr, j, 0, xwh, lane, acc); j += 4; }
        int rem = end - j;
        if (rem > 0) batch_f128<4, true>(csr, j, rem, xwh, lane, acc);

        float2 bv = ((const float2*)bias)[lane];
        float ox = fmaf(di, (acc[0].x + acc[1].x) + (acc[2].x + acc[3].x),
                        fmaf(x0.x, d2, bv.x));
        float oy = fmaf(di, (acc[0].y + acc[1].y) + (acc[2].y + acc[3].y),
                        fmaf(x0.y, d2, bv.y));
        unsigned short h0 = bf16_rne(ox);
        unsigned short l0 = bf16_rne(ox - bf16_f(h0));
        unsigned short h1 = bf16_rne(oy);
        unsigned short l1 = bf16_rne(oy - bf16_f(h1));
        ((unsigned*)(outHi + (size_t)i * F))[lane] = (unsigned)h0 | ((unsigned)h1 << 16);
        ((unsigned*)(outLo + (size_t)i * F))[lane] = (unsigned)l0 | ((unsigned)l1 << 16);
    } else {  // F == 64, final layer
        float x0 = xw[(size_t)i * F + lane];
        float acc[4] = {0.f, 0.f, 0.f, 0.f};

        for (; j + 16 <= end; j += 16) batch_f64<16, false>(csr, j, 0, xwh, lane, acc);
        if (j + 8 <= end) { batch_f64<8, false>(csr, j, 0, xwh, lane, acc); j += 8; }
        if (j + 4 <= end) { batch_f64<4, false>(csr, j, 0, xwh, lane, acc); j += 4; }
        int rem = end - j;
        if (rem > 0) batch_f64<4, true>(csr, j, rem, xwh, lane, acc);

        float o = fmaf(di, (acc[0] + acc[1]) + (acc[2] + acc[3]),
                       fmaf(x0, d2, bias[lane]));
        o = fmaxf(o, 0.f);
        out[(size_t)i * F + lane] = o;
    }
}

extern "C" void kernel_launch(void* const* d_in, const int* in_sizes, int n_in,
                              void* d_out, int out_size, void* d_ws, size_t ws_size,
                              hipStream_t stream) {
    const float* x  = (const float*)d_in[0];
    const int*   ei = (const int*)d_in[1];
    const float* W1 = (const float*)d_in[2];
    const float* b1 = (const float*)d_in[3];
    const float* W2 = (const float*)d_in[4];
    const float* b2 = (const float*)d_in[5];
    const float* W3 = (const float*)d_in[6];
    const float* b3 = (const float*)d_in[7];
    float* out = (float*)d_out;

    int E = in_sizes[1] / 2;
    int n = in_sizes[0] / C_IN;
    const int* src = ei;
    const int* dst = ei + E;
    int nbuk = (n + 255) >> 8;

    // workspace layout (16B-aligned segments)
    float*          A    = (float*)d_ws;                        // [n*128] gemm Y fp32
    __half*         Ah   = (__half*)(A + (size_t)n * C_HID);    // [n*128] dinv*Y fp16
    unsigned short* Bhi  = (unsigned short*)(Ah + (size_t)n * C_HID); // [n*128] bf16 hi
    unsigned short* Blo  = Bhi + (size_t)n * C_HID;             // [n*128] bf16 lo
    unsigned short* Wf   = Blo + (size_t)n * C_HID;             // [81920] frag W
    int2*           ebuf = (int2*)(Wf + 81920);                 // [E]
    int*            csr  = (int*)(ebuf + E);                    // [E]
    float*          dinv = (float*)(csr + E);                   // [n]
    int*            rowptr = (int*)(dinv + n);                  // [n+1]
    int*            bukCnt = rowptr + n + 1;                    // [256]
    int*            bbase  = bukCnt + 256;                      // [nbuk+1]
    int*            cursor = bbase + 256 + 1;                   // [256]

    unsigned short* W1h = Wf;
    unsigned short* W1l = Wf + 16384;
    unsigned short* W2h = Wf + 32768;
    unsigned short* W2l = Wf + 49152;
    unsigned short* W3h = Wf + 65536;
    unsigned short* W3l = Wf + 73728;

    // ---- CSR build ----
    hipMemsetAsync(bukCnt, 0, 256 * sizeof(int), stream);
    buk_hist_kernel<<<PART_BLOCKS, 256, 0, stream>>>(dst, E, bukCnt);
    buk_scan_kernel<<<1, 256, 0, stream>>>(bukCnt, nbuk, E, bbase, cursor);
    buk_place_kernel<<<PART_BLOCKS, 256, 0, stream>>>(src, dst, E, cursor, ebuf);
    buk_fill_kernel<<<nbuk, 256, 0, stream>>>(ebuf, bbase, n, E, rowptr, dinv, csr);

    // ---- one-time W frag split ----
    wsplit_all_kernel<<<20, 256, 0, stream>>>(W1, W2, W3, Wf);

    int aggBlocks = (n + 3) / 4;
    int rowTiles = (n + 63) / 64;   // 782

    // ---- layer 1 (fp32 x, in-register split) ----
    gemm1_mfma<<<rowTiles * 2, 256, 0, stream>>>(x, W1h, W1l, dinv, A, Ah, n);
    agg_kernel<C_HID, 0><<<aggBlocks, 256, 0, stream>>>(rowptr, csr, A, Ah, dinv, b1,
                                                        nullptr, Bhi, Blo, n);
    // ---- layer 2 ----
    gemm_mfma<C_HID><<<rowTiles * 2, 256, 0, stream>>>(Bhi, Blo, W2h, W2l, dinv, A, Ah, n);
    agg_kernel<C_HID, 0><<<aggBlocks, 256, 0, stream>>>(rowptr, csr, A, Ah, dinv, b2,
                                                        nullptr, Bhi, Blo, n);
    // ---- layer 3 ----
    gemm_mfma<C_OUT><<<rowTiles, 256, 0, stream>>>(Bhi, Blo, W3h, W3l, dinv, A, Ah, n);
    agg_kernel<C_OUT, 1><<<aggBlocks, 256, 0, stream>>>(rowptr, csr, A, Ah, dinv, b3,
                                                        out, nullptr, nullptr, n);
}